// Round 11
// baseline (217.856 us; speedup 1.0000x reference)
//
#include <hip/hip_runtime.h>
#include <hip/hip_bf16.h>
#include <stdint.h>

#define IN_F 4096
#define OUT_F 11008
#define NUM_CH 128
#define NUM_NORM 3968
#define BATCH 64
#define KSPLIT 16
#define KCHUNK 256               // k per block = 8 substeps of 32
#define NSUB 8
#define NTILE 256                // n per block
#define BS 40                    // shorts per col (16 dw data + 4 dw pad)

typedef short short8 __attribute__((ext_vector_type(8)));
typedef float float4v __attribute__((ext_vector_type(4)));
typedef int int4v __attribute__((ext_vector_type(4)));

// Barrier WITHOUT the implicit vmcnt(0) drain of __syncthreads(): waits only
// this wave's LDS ops; global prefetch stays in flight across it (R9-proven).
__device__ __forceinline__ void barrier_no_vmcnt() {
    asm volatile("s_waitcnt lgkmcnt(0)\n\ts_barrier" ::: "memory");
}

__device__ __forceinline__ unsigned short f2bf(float f) {
    union { float f; unsigned u; } v; v.f = f;
    unsigned u = v.u;
    return (unsigned short)((u + 0x7FFFu + ((u >> 16) & 1u)) >> 16);
}

__device__ __forceinline__ unsigned pk_bf16(float lo, float hi) {
    __hip_bfloat162 h = __float22bfloat162_rn(make_float2(lo, hi));  // v_cvt_pk_bf16_f32
    union { __hip_bfloat162 h; unsigned u; } c; c.h = h; return c.u;
}

// Gather-permute x into bf16 xp[64][4096]
__global__ __launch_bounds__(256) void permute_x(
        const float* __restrict__ x, const int* __restrict__ cidx,
        unsigned short* __restrict__ xp) {
    int i = blockIdx.x * blockDim.x + threadIdx.x;
    int b = blockIdx.y;
    int lo = 0, hi = NUM_CH;
    while (lo < hi) { int mid = (lo + hi) >> 1; if (cidx[mid] < i) lo = mid + 1; else hi = mid; }
    bool isch = (lo < NUM_CH) && (cidx[lo] == i);
    int pos = isch ? (NUM_NORM + lo) : (i - lo);
    xp[b * IN_F + pos] = f2bf(x[b * IN_F + i]);
}

// out[m][n] = bias[n] + sum_ky part[ky][m][n]
__global__ __launch_bounds__(256) void reduce_out(
        const float* __restrict__ part, const float* __restrict__ bias,
        float* __restrict__ out) {
    const int i = blockIdx.x * 256 + threadIdx.x;          // float4 index
    const int c = i % (OUT_F / 4);
    float4v s = *reinterpret_cast<const float4v*>(bias + c * 4);
    #pragma unroll
    for (int ky = 0; ky < KSPLIT; ++ky) {
        const float4v p = reinterpret_cast<const float4v*>(
            part + (size_t)ky * BATCH * OUT_F)[i];
        s = (float4v){s[0] + p[0], s[1] + p[1], s[2] + p[2], s[3] + p[3]};
    }
    reinterpret_cast<float4v*>(out)[i] = s;
}

// Fused dequant + bf16 MFMA GEMM, 256-wide N-tile so every qweight row is
// read as ONE contiguous 1-KB chunk per wave-instruction (vs 256 B before) --
// A/B test of the DRAM/L3 access-granularity theory. 8 x 32-k substeps, dbuf
// LDS, light barriers, q+A prefetch one substep ahead.
// LDS k-layout per col: 4 dword-groups of 4, group g holds k=8g..8g+7,
// physically stored at group g ^ ((n>>2)&3) (XOR swizzle, cuts write conflicts).
__global__ void qgemm(
        const unsigned short* __restrict__ xp, const int* __restrict__ qw,
        const float* __restrict__ cw, const float* __restrict__ scales,
        float* __restrict__ part) {
    __shared__ unsigned short Bt[2][NTILE][BS];   // 2 x 20 KB

    const int tid  = threadIdx.x;
    const int wave = tid >> 6;
    const int lane = tid & 63;
    const int ln   = lane & 15;
    const int lq   = lane >> 4;
    const int n0    = blockIdx.x * NTILE;
    const int ky    = blockIdx.y;
    const int kbase = ky * KCHUNK;

    // staging mapping: wave = row group, lane covers 4 consecutive n
    const int nb = (tid & 63) << 2;      // n offset 0..252
    const int rg = tid >> 6;             // 0..3 (4 rows each)

    const int*   qbase = qw + n0 + nb;
    const float* sbase = scales + n0 + nb;
    const float* cbase = cw + n0 + nb;

    // scales for the (up to) 2 groups this chunk touches
    float4v scg[2];
    scg[0] = *reinterpret_cast<const float4v*>(sbase + (size_t)(2 * ky) * OUT_F);
    scg[1] = (2 * ky + 1 <= 30)
        ? *reinterpret_cast<const float4v*>(sbase + (size_t)(2 * ky + 1) * OUT_F)
        : scg[0];

    float4v acc[4][4];   // [mt][nf]
    #pragma unroll
    for (int a = 0; a < 4; ++a)
        #pragma unroll
        for (int b = 0; b < 4; ++b) acc[a][b] = (float4v){0.f, 0.f, 0.f, 0.f};

    // ---- prologue: substep-0 q rows + A frags ----
    int4v qc[4];
    {
        const size_t rb = (size_t)(kbase >> 1) + 4 * rg;
        #pragma unroll
        for (int i = 0; i < 4; ++i)
            qc[i] = *reinterpret_cast<const int4v*>(qbase + (rb + i) * OUT_F);
    }
    short8 acur[4];
    #pragma unroll
    for (int mt = 0; mt < 4; ++mt)
        acur[mt] = *reinterpret_cast<const short8*>(
            xp + (size_t)(mt * 16 + ln) * IN_F + kbase + (lq << 3));

    for (int s = 0; s < NSUB; ++s) {
        const int k0 = kbase + 32 * s;
        unsigned short (*buf)[BS] = Bt[s & 1];
        const bool normal = (k0 < NUM_NORM);

        if (normal) {
            const int4v q0 = qc[0], q1 = qc[1], q2 = qc[2], q3 = qc[3];
            const float4v sc = scg[s >> 2];
            // prefetch next substep's q rows (stays in flight across barrier)
            if (s + 1 < NSUB && k0 + 32 < NUM_NORM) {
                const size_t rb = (size_t)((k0 + 32) >> 1) + 4 * rg;
                #pragma unroll
                for (int i = 0; i < 4; ++i)
                    qc[i] = *reinterpret_cast<const int4v*>(qbase + (rb + i) * OUT_F);
            }
            const int4v qq[4] = {q0, q1, q2, q3};
            // dequant: col nb+cc gets k-run 8*rg..8*rg+7 (rows 4rg..4rg+3)
            #pragma unroll
            for (int cc = 0; cc < 4; ++cc) {
                const int n = nb + cc;
                union { short8 v; unsigned u[4]; } wv;
                const float s1 = sc[cc];
                #pragma unroll
                for (int i = 0; i < 4; ++i) {
                    const int q = qq[i][cc];
                    wv.u[i] = pk_bf16((float)((q & 0xF) - 8) * s1,
                                      (float)(((q >> 4) & 0xF) - 8) * s1);
                }
                const int gp = rg ^ ((n >> 2) & 3);   // XOR-swizzled group
                *reinterpret_cast<short8*>(&buf[n][gp << 3]) = wv.v;
            }
        } else {
            // cherry substep (ky==15, s>=4): 32 fp32 rows x 256 n
            const int crow0 = 32 * s - 128;           // k0 - NUM_NORM
            #pragma unroll
            for (int j = 0; j < 8; ++j) {
                const int kl = 8 * rg + j;            // local k 0..31
                const float4v ch = *reinterpret_cast<const float4v*>(
                    cbase + (size_t)(crow0 + kl) * OUT_F);
                #pragma unroll
                for (int i = 0; i < 4; ++i) {
                    const int n = nb + i;
                    const int g = kl >> 3, go = kl & 7;
                    const int gp = g ^ ((n >> 2) & 3);
                    buf[n][(gp << 3) + go] = f2bf(ch[i]);
                }
            }
        }
        // prefetch next substep's A frags
        short8 anxt[4];
        if (s + 1 < NSUB) {
            #pragma unroll
            for (int mt = 0; mt < 4; ++mt)
                anxt[mt] = *reinterpret_cast<const short8*>(
                    xp + (size_t)(mt * 16 + ln) * IN_F + k0 + 32 + (lq << 3));
        }

        barrier_no_vmcnt();   // LDS order only; vmem stays in flight

        // B frags: wave's 4 n-frags (n = nf*64 + wave*16 + ln)
        short8 bf[4];
        #pragma unroll
        for (int nf = 0; nf < 4; ++nf) {
            const int n = nf * 64 + (wave << 4) + ln;
            const int gp = lq ^ ((n >> 2) & 3);
            bf[nf] = *reinterpret_cast<const short8*>(&buf[n][gp << 3]);
        }
        #pragma unroll
        for (int mt = 0; mt < 4; ++mt)
            #pragma unroll
            for (int nf = 0; nf < 4; ++nf)
                acc[mt][nf] = __builtin_amdgcn_mfma_f32_16x16x32_bf16(
                    acur[mt], bf[nf], acc[mt][nf], 0, 0, 0);

        if (s + 1 < NSUB) {
            #pragma unroll
            for (int mt = 0; mt < 4; ++mt) acur[mt] = anxt[mt];
        }
    }

    // Epilogue: D col = ln -> n, row = lq*4+r -> m; plain partial stores
    float* pbase = part + (size_t)ky * BATCH * OUT_F;
    #pragma unroll
    for (int mt = 0; mt < 4; ++mt) {
        #pragma unroll
        for (int nf = 0; nf < 4; ++nf) {
            const int n = n0 + nf * 64 + (wave << 4) + ln;
            #pragma unroll
            for (int r = 0; r < 4; ++r) {
                const int m = mt * 16 + (lq << 2) + r;
                pbase[(size_t)m * OUT_F + n] = acc[mt][nf][r];
            }
        }
    }
}

extern "C" void kernel_launch(void* const* d_in, const int* in_sizes, int n_in,
                              void* d_out, int out_size, void* d_ws, size_t ws_size,
                              hipStream_t stream) {
    const float* x      = (const float*)d_in[0];
    const int*   qw     = (const int*)d_in[1];     // uint8 widened to int32 by harness
    const float* cw     = (const float*)d_in[2];
    const int*   cidx   = (const int*)d_in[3];
    const float* scales = (const float*)d_in[4];
    const float* bias   = (const float*)d_in[5];
    float*       out    = (float*)d_out;

    unsigned short* xp   = (unsigned short*)d_ws;                    // 512 KB
    float*          part = (float*)((char*)d_ws + (512 << 10));      // 16*64*11008*4 = 45 MB

    dim3 pgrid(IN_F / 256, BATCH);
    permute_x<<<pgrid, 256, 0, stream>>>(x, cidx, xp);
    qgemm<<<dim3(OUT_F / NTILE, KSPLIT), 256, 0, stream>>>(xp, qw, cw, scales, part);
    reduce_out<<<(BATCH * OUT_F / 4) / 256, 256, 0, stream>>>(part, bias, out);
}

// Round 12
// 173.293 us; speedup vs baseline: 1.2572x; 1.2572x over previous
//
#include <hip/hip_runtime.h>
#include <hip/hip_bf16.h>
#include <stdint.h>

#define IN_F 4096
#define OUT_F 11008
#define NUM_CH 128
#define NUM_NORM 3968
#define BATCH 64
#define KSPLIT 16
#define KCHUNK 256               // k per block = 8 substeps of 32
#define NSUB 8
#define NTILE 256                // n per block
#define BS 40                    // shorts per col (16 dw data + 4 dw pad)
#define TS 264                   // epilogue transpose tile stride (shorts)

typedef short short8 __attribute__((ext_vector_type(8)));
typedef float float4v __attribute__((ext_vector_type(4)));
typedef int int4v __attribute__((ext_vector_type(4)));
typedef unsigned short ushort8 __attribute__((ext_vector_type(8)));

// Barrier WITHOUT the implicit vmcnt(0) drain of __syncthreads(): waits only
// this wave's LDS ops; global prefetch stays in flight across it (R9-proven).
__device__ __forceinline__ void barrier_no_vmcnt() {
    asm volatile("s_waitcnt lgkmcnt(0)\n\ts_barrier" ::: "memory");
}

__device__ __forceinline__ unsigned short f2bf(float f) {
    union { float f; unsigned u; } v; v.f = f;
    unsigned u = v.u;
    return (unsigned short)((u + 0x7FFFu + ((u >> 16) & 1u)) >> 16);
}

__device__ __forceinline__ unsigned pk_bf16(float lo, float hi) {
    __hip_bfloat162 h = __float22bfloat162_rn(make_float2(lo, hi));  // v_cvt_pk_bf16_f32
    union { __hip_bfloat162 h; unsigned u; } c; c.h = h; return c.u;
}

// Gather-permute x into bf16 xp[64][4096]
__global__ __launch_bounds__(256) void permute_x(
        const float* __restrict__ x, const int* __restrict__ cidx,
        unsigned short* __restrict__ xp) {
    int i = blockIdx.x * blockDim.x + threadIdx.x;
    int b = blockIdx.y;
    int lo = 0, hi = NUM_CH;
    while (lo < hi) { int mid = (lo + hi) >> 1; if (cidx[mid] < i) lo = mid + 1; else hi = mid; }
    bool isch = (lo < NUM_CH) && (cidx[lo] == i);
    int pos = isch ? (NUM_NORM + lo) : (i - lo);
    xp[b * IN_F + pos] = f2bf(x[b * IN_F + i]);
}

// out[m][n] = bias[n] + sum_ky part_bf16[ky][m][n]
__global__ __launch_bounds__(256) void reduce_out(
        const unsigned short* __restrict__ part, const float* __restrict__ bias,
        float* __restrict__ out) {
    const int i = blockIdx.x * 256 + threadIdx.x;          // ushort8 index
    const int c = i % (OUT_F / 8);
    float s[8];
    #pragma unroll
    for (int j = 0; j < 8; ++j) s[j] = bias[c * 8 + j];
    #pragma unroll
    for (int ky = 0; ky < KSPLIT; ++ky) {
        const ushort8 p = reinterpret_cast<const ushort8*>(
            part + (size_t)ky * BATCH * OUT_F)[i];
        #pragma unroll
        for (int j = 0; j < 8; ++j) {
            union { unsigned u; float f; } v; v.u = ((unsigned)p[j]) << 16;
            s[j] += v.f;
        }
    }
    float4v* o = reinterpret_cast<float4v*>(out) + i * 2;
    o[0] = (float4v){s[0], s[1], s[2], s[3]};
    o[1] = (float4v){s[4], s[5], s[6], s[7]};
}

// Fused dequant + bf16 MFMA GEMM. R11 structure (256-n tile -> every qweight
// row read as ONE 1-KB contiguous chunk per wave instruction; proven 2.5 TB/s)
// with the spill fixed: __launch_bounds__(256,2) gives the 256-VGPR budget the
// 16-accumulator tile actually needs. Partials stored bf16 via LDS-transposed
// full-line dwordx4 stores.
__global__ __launch_bounds__(256, 2) void qgemm(
        const unsigned short* __restrict__ xp, const int* __restrict__ qw,
        const float* __restrict__ cw, const float* __restrict__ scales,
        unsigned short* __restrict__ part) {
    __shared__ unsigned short Bt[2][NTILE][BS];   // 40 KB; reused by epilogue

    const int tid  = threadIdx.x;
    const int wave = tid >> 6;
    const int lane = tid & 63;
    const int ln   = lane & 15;
    const int lq   = lane >> 4;
    const int n0    = blockIdx.x * NTILE;
    const int ky    = blockIdx.y;
    const int kbase = ky * KCHUNK;

    // staging mapping: wave rg covers 4 consecutive packed rows, full 256-int width
    const int nb = (tid & 63) << 2;      // n offset 0..252 (4 ints per lane)
    const int rg = tid >> 6;             // row group 0..3

    const int*   qbase = qw + n0 + nb;
    const float* sbase = scales + n0 + nb;
    const float* cbase = cw + n0 + nb;

    // scales for the (up to) 2 groups this chunk touches
    float4v scg[2];
    scg[0] = *reinterpret_cast<const float4v*>(sbase + (size_t)(2 * ky) * OUT_F);
    scg[1] = (2 * ky + 1 <= 30)
        ? *reinterpret_cast<const float4v*>(sbase + (size_t)(2 * ky + 1) * OUT_F)
        : scg[0];

    float4v acc[4][4];   // [mt][nf]
    #pragma unroll
    for (int a = 0; a < 4; ++a)
        #pragma unroll
        for (int b = 0; b < 4; ++b) acc[a][b] = (float4v){0.f, 0.f, 0.f, 0.f};

    // ---- prologue: substep-0 q rows + A frags ----
    int4v qc[4];
    {
        const size_t rb = (size_t)(kbase >> 1) + 4 * rg;
        #pragma unroll
        for (int i = 0; i < 4; ++i)
            qc[i] = *reinterpret_cast<const int4v*>(qbase + (rb + i) * OUT_F);
    }
    short8 acur[4];
    #pragma unroll
    for (int mt = 0; mt < 4; ++mt)
        acur[mt] = *reinterpret_cast<const short8*>(
            xp + (size_t)(mt * 16 + ln) * IN_F + kbase + (lq << 3));

    for (int s = 0; s < NSUB; ++s) {
        const int k0 = kbase + 32 * s;
        unsigned short (*buf)[BS] = Bt[s & 1];
        const bool normal = (k0 < NUM_NORM);

        if (normal) {
            const int4v q0 = qc[0], q1 = qc[1], q2 = qc[2], q3 = qc[3];
            const float4v sc = scg[s >> 2];
            // prefetch next substep's q rows (stays in flight across barrier)
            if (s + 1 < NSUB && k0 + 32 < NUM_NORM) {
                const size_t rb = (size_t)((k0 + 32) >> 1) + 4 * rg;
                #pragma unroll
                for (int i = 0; i < 4; ++i)
                    qc[i] = *reinterpret_cast<const int4v*>(qbase + (rb + i) * OUT_F);
            }
            const int4v qq[4] = {q0, q1, q2, q3};
            // dequant: col nb+cc gets k-run 8*rg..8*rg+7 (rows 4rg..4rg+3)
            #pragma unroll
            for (int cc = 0; cc < 4; ++cc) {
                const int n = nb + cc;
                union { short8 v; unsigned u[4]; } wv;
                const float s1 = sc[cc];
                #pragma unroll
                for (int i = 0; i < 4; ++i) {
                    const int q = qq[i][cc];
                    wv.u[i] = pk_bf16((float)((q & 0xF) - 8) * s1,
                                      (float)(((q >> 4) & 0xF) - 8) * s1);
                }
                const int gp = rg ^ ((n >> 2) & 3);   // XOR-swizzled group
                *reinterpret_cast<short8*>(&buf[n][gp << 3]) = wv.v;
            }
        } else {
            // cherry substep (ky==15, s>=4): 32 fp32 rows x 256 n
            const int crow0 = 32 * s - 128;           // k0 - NUM_NORM
            #pragma unroll
            for (int j = 0; j < 8; ++j) {
                const int kl = 8 * rg + j;            // local k 0..31
                const float4v ch = *reinterpret_cast<const float4v*>(
                    cbase + (size_t)(crow0 + kl) * OUT_F);
                #pragma unroll
                for (int i = 0; i < 4; ++i) {
                    const int n = nb + i;
                    const int g = kl >> 3, go = kl & 7;
                    const int gp = g ^ ((n >> 2) & 3);
                    buf[n][(gp << 3) + go] = f2bf(ch[i]);
                }
            }
        }
        // prefetch next substep's A frags
        short8 anxt[4];
        if (s + 1 < NSUB) {
            #pragma unroll
            for (int mt = 0; mt < 4; ++mt)
                anxt[mt] = *reinterpret_cast<const short8*>(
                    xp + (size_t)(mt * 16 + ln) * IN_F + k0 + 32 + (lq << 3));
        }

        barrier_no_vmcnt();   // LDS order only; vmem stays in flight

        // B frags: wave's 4 n-frags (n = nf*64 + wave*16 + ln)
        short8 bf[4];
        #pragma unroll
        for (int nf = 0; nf < 4; ++nf) {
            const int n = nf * 64 + (wave << 4) + ln;
            const int gp = lq ^ ((n >> 2) & 3);
            bf[nf] = *reinterpret_cast<const short8*>(&buf[n][gp << 3]);
        }
        #pragma unroll
        for (int mt = 0; mt < 4; ++mt)
            #pragma unroll
            for (int nf = 0; nf < 4; ++nf)
                acc[mt][nf] = __builtin_amdgcn_mfma_f32_16x16x32_bf16(
                    acur[mt], bf[nf], acc[mt][nf], 0, 0, 0);

        if (s + 1 < NSUB) {
            #pragma unroll
            for (int mt = 0; mt < 4; ++mt) acur[mt] = anxt[mt];
        }
    }

    // ---- epilogue: transpose through LDS, store bf16 partials as full lines ----
    barrier_no_vmcnt();          // all waves' MFMA LDS reads complete
    unsigned short* T = &Bt[0][0][0];   // reuse as [64][TS] bf16 (33.8 KB <= 40 KB)
    #pragma unroll
    for (int mt = 0; mt < 4; ++mt) {
        #pragma unroll
        for (int nf = 0; nf < 4; ++nf) {
            const int nl = nf * 64 + (wave << 4) + ln;
            #pragma unroll
            for (int r = 0; r < 4; ++r) {
                const int m = mt * 16 + (lq << 2) + r;
                T[m * TS + nl] = f2bf(acc[mt][nf][r]);
            }
        }
    }
    barrier_no_vmcnt();
    // cooperative readout: thread covers row m = tid>>2, 64 consecutive n
    {
        const int m  = tid >> 2;
        const int c0 = (tid & 3) * 64;
        unsigned short* dst = part + (size_t)ky * BATCH * OUT_F
                              + (size_t)m * OUT_F + n0 + c0;
        const unsigned short* src = T + m * TS + c0;
        #pragma unroll
        for (int j = 0; j < 8; ++j)
            *reinterpret_cast<ushort8*>(dst + j * 8) =
                *reinterpret_cast<const ushort8*>(src + j * 8);
    }
}

extern "C" void kernel_launch(void* const* d_in, const int* in_sizes, int n_in,
                              void* d_out, int out_size, void* d_ws, size_t ws_size,
                              hipStream_t stream) {
    const float* x      = (const float*)d_in[0];
    const int*   qw     = (const int*)d_in[1];     // uint8 widened to int32 by harness
    const float* cw     = (const float*)d_in[2];
    const int*   cidx   = (const int*)d_in[3];
    const float* scales = (const float*)d_in[4];
    const float* bias   = (const float*)d_in[5];
    float*       out    = (float*)d_out;

    unsigned short* xp   = (unsigned short*)d_ws;                         // 512 KB
    unsigned short* part = (unsigned short*)((char*)d_ws + (512 << 10));  // 16*64*11008*2 = 22.5 MB

    dim3 pgrid(IN_F / 256, BATCH);
    permute_x<<<pgrid, 256, 0, stream>>>(x, cidx, xp);
    qgemm<<<dim3(OUT_F / NTILE, KSPLIT), 256, 0, stream>>>(xp, qw, cw, scales, part);
    reduce_out<<<(BATCH * OUT_F / 8) / 256, 256, 0, stream>>>(part, bias, out);
}